// Round 6
// baseline (8532.030 us; speedup 1.0000x reference)
//
#include <hip/hip_runtime.h>
#include <hip/hip_bf16.h>

typedef short  short8 __attribute__((ext_vector_type(8)));
typedef float  f32x4  __attribute__((ext_vector_type(4)));
using ushort = unsigned short;
using uint   = unsigned int;

#define KP  1152               // padded K: 1024 (h) + 128 (x)
#define XP  128                // bf16 x row stride
#define AL  __ATOMIC_RELAXED
#define SC  __HIP_MEMORY_SCOPE_AGENT
#define MFMA __builtin_amdgcn_mfma_f32_16x16x32_bf16

__device__ __forceinline__ ushort f2bf(float f) {
    uint u = __float_as_uint(f);
    return (ushort)((u + 0x7fffu + ((u >> 16) & 1u)) >> 16);  // RNE
}
// async global->LDS, 16B/lane, aux=1 (sc0): L1-bypass, L2-hit — XCD-coherent
__device__ __forceinline__ void gld16(const void* g, void* l) {
    __builtin_amdgcn_global_load_lds(
        (const __attribute__((address_space(1))) uint*)g,
        (__attribute__((address_space(3))) uint*)l, 16, 0, 1);
}

// one-time global barrier (256 blocks) with agent release/acquire fences
__device__ __forceinline__ void globalbar(uint* ctr, uint* gen) {
    __syncthreads();
    if (threadIdx.x == 0) {
        __builtin_amdgcn_fence(__ATOMIC_RELEASE, "agent");
        uint g = __hip_atomic_load(gen, AL, SC);
        uint old = __hip_atomic_fetch_add(ctr, 1u, AL, SC);
        if (old == (g + 1u) * 256u - 1u) __hip_atomic_fetch_add(gen, 1u, AL, SC);
        while (__hip_atomic_load(gen, AL, SC) == g) __builtin_amdgcn_s_sleep(8);
        __builtin_amdgcn_fence(__ATOMIC_ACQUIRE, "agent");
    }
    __syncthreads();
}
// per-team barrier: relaxed, monotonic counter, NO cache maintenance
__device__ __forceinline__ void teambar(uint* ctr, uint* gen, uint c) {
    __syncthreads();
    if (threadIdx.x == 0) {
        uint g = __hip_atomic_load(gen, AL, SC);
        uint old = __hip_atomic_fetch_add(ctr, 1u, AL, SC);
        if (old == (g + 1u) * c - 1u) __hip_atomic_fetch_add(gen, 1u, AL, SC);
        while (__hip_atomic_load(gen, AL, SC) == g) __builtin_amdgcn_s_sleep(2);
    }
    __syncthreads();
}

#define GRU_KK(AN)                                                                 \
    {                                                                              \
        short8 b0 = bq[st & 1][kk][0], b1 = bq[st & 1][kk][1], b2 = bq[st & 1][kk][2]; \
        if (pref) {                                                               \
            const int off = ((st + 2) * 8 + wk * 4 + kk) * 32;                    \
            bq[st & 1][kk][0] = *(const short8*)(bpr0 + off);                     \
            bq[st & 1][kk][1] = *(const short8*)(bpr1 + off);                     \
            bq[st & 1][kk][2] = *(const short8*)(bpr2 + off);                     \
        }                                                                          \
        const int g = (wk * 4 + kk) * 4 + quad;                                   \
        const int ch = (g & 16) | ((g & 15) ^ l16);                               \
        const ushort* ap_ = ab + l16 * 256 + ch * 8;                              \
        short8 a0 = *(const short8*)(ap_);                                        \
        short8 a1 = *(const short8*)(ap_ + 4096);                                 \
        short8 a2 = *(const short8*)(ap_ + 8192);                                 \
        short8 a3 = *(const short8*)(ap_ + 12288);                                \
        accR[0] = MFMA(a0, b0, accR[0], 0, 0, 0);                                 \
        accZ[0] = MFMA(a0, b1, accZ[0], 0, 0, 0);                                 \
        AN[0]   = MFMA(a0, b2, AN[0],   0, 0, 0);                                 \
        accR[1] = MFMA(a1, b0, accR[1], 0, 0, 0);                                 \
        accZ[1] = MFMA(a1, b1, accZ[1], 0, 0, 0);                                 \
        AN[1]   = MFMA(a1, b2, AN[1],   0, 0, 0);                                 \
        accR[2] = MFMA(a2, b0, accR[2], 0, 0, 0);                                 \
        accZ[2] = MFMA(a2, b1, accZ[2], 0, 0, 0);                                 \
        AN[2]   = MFMA(a2, b2, AN[2],   0, 0, 0);                                 \
        accR[3] = MFMA(a3, b0, accR[3], 0, 0, 0);                                 \
        accZ[3] = MFMA(a3, b1, accZ[3], 0, 0, 0);                                 \
        AN[3]   = MFMA(a3, b2, AN[3],   0, 0, 0);                                 \
    }

// One GRU block-tile: 64 rows (bmBase+mt*64) x 64 n-cols (nt) x 3 gates, K=1152.
__device__ __forceinline__ void gru_tile(
    int T, uint xcc, int wave, int lane, int wk, int wn, int quad, int l16,
    const ushort* hsrc, const ushort* xsrc, ushort* hdst,
    const ushort* wpack, const float* b_ih, const float* b_hh, float* hfx,
    ushort* lds)
{
    const int mt = T >> 4, nt = T & 15;
    const int bmBase = (int)xcc * 128 + mt * 64;

    auto stageA = [&](int st, int buf) {
#pragma unroll
        for (int i = 0; i < 4; ++i) {
            const int cx = (wave * 4 + i) * 64 + lane;
            const int row = cx >> 5, chunk = cx & 31;
            const int kb = chunk >> 4, j = chunk & 15;
            const int gl = ((kb << 4) | (j ^ (row & 15))) * 8;
            ushort* dst = lds + buf * 16384 + (wave * 4 + i) * 512;
            if (st < 4)
                gld16(hsrc + (size_t)(bmBase + row) * 1024 + st * 256 + gl, dst);
            else if (gl < 128)
                gld16(xsrc + (size_t)(bmBase + row) * XP + gl, dst);
        }
    };
    const int rowN = nt * 64 + wn * 16 + l16;
    const ushort* bpr0 = wpack + (size_t)rowN * KP + quad * 8;
    const ushort* bpr1 = bpr0 + (size_t)1024 * KP;
    const ushort* bpr2 = bpr0 + (size_t)2048 * KP;

    f32x4 accR[4], accZ[4], accNH[4], accNI[4];
#pragma unroll
    for (int i = 0; i < 4; ++i) {
        accR[i] = (f32x4){0.f,0.f,0.f,0.f}; accZ[i] = (f32x4){0.f,0.f,0.f,0.f};
        accNH[i] = (f32x4){0.f,0.f,0.f,0.f}; accNI[i] = (f32x4){0.f,0.f,0.f,0.f};
    }
    short8 bq[2][4][3];                    // depth-2-stage B prefetch (~930 cyc cover)
#pragma unroll
    for (int p = 0; p < 2; ++p)
#pragma unroll
        for (int kk = 0; kk < 4; ++kk) {
            const int off = (p * 8 + wk * 4 + kk) * 32;
            bq[p][kk][0] = *(const short8*)(bpr0 + off);
            bq[p][kk][1] = *(const short8*)(bpr1 + off);
            bq[p][kk][2] = *(const short8*)(bpr2 + off);
        }
    stageA(0, 0);
    __syncthreads();
#pragma unroll 1
    for (int st = 0; st < 5; ++st) {
        if (st < 4) stageA(st + 1, (st + 1) & 1);
        const ushort* ab = lds + (st & 1) * 16384;
        const bool pref = (st < 2) || (st == 2 && wk == 0);
        if (st < 4) {
#pragma unroll
            for (int kk = 0; kk < 4; ++kk) GRU_KK(accNH)
        } else if (wk == 0) {              // stage 4 = x-part, 128 cols, wk0 only
#pragma unroll
            for (int kk = 0; kk < 4; ++kk) GRU_KK(accNI)
        }
        __syncthreads();
    }
    // cross-wk reduction through LDS
    f32x4* red = (f32x4*)lds;
    const int rslot = wn * 64 + lane;
    if (wk == 1) {
#pragma unroll
        for (int mq = 0; mq < 4; ++mq) {
            red[mq * 256 + rslot]        = accR[mq];
            red[1024 + mq * 256 + rslot] = accZ[mq];
        }
    }
    __syncthreads();
    if (wk == 0) {
#pragma unroll
        for (int mq = 0; mq < 4; ++mq) {
            accR[mq] += red[mq * 256 + rslot];
            accZ[mq] += red[1024 + mq * 256 + rslot];
        }
    }
    __syncthreads();
    if (wk == 1) {
#pragma unroll
        for (int mq = 0; mq < 4; ++mq) {
            red[mq * 256 + rslot]        = accNH[mq];
            red[1024 + mq * 256 + rslot] = accNI[mq];
        }
    }
    __syncthreads();
    if (wk == 0) {
#pragma unroll
        for (int mq = 0; mq < 4; ++mq) {
            accNH[mq] += red[mq * 256 + rslot];
            accNI[mq] += red[1024 + mq * 256 + rslot];
        }
        const float bir = b_ih[rowN],        bhr = b_hh[rowN];
        const float biz = b_ih[1024 + rowN], bhz = b_hh[1024 + rowN];
        const float bin_= b_ih[2048 + rowN], bhn = b_hh[2048 + rowN];
#pragma unroll
        for (int mq = 0; mq < 4; ++mq) {
#pragma unroll
            for (int r = 0; r < 4; ++r) {
                const int m = bmBase + mq * 16 + quad * 4 + r;
                float gr = accR[mq][r] + bir + bhr;
                float gz = accZ[mq][r] + biz + bhz;
                float rg = 1.f / (1.f + __expf(-gr));
                float zg = 1.f / (1.f + __expf(-gz));
                float nx = accNI[mq][r] + bin_ + rg * (accNH[mq][r] + bhn);
                nx = fminf(30.f, fmaxf(-30.f, nx));
                float e  = __expf(-2.f * nx);
                float ng = (1.f - e) / (1.f + e);
                float hp = hfx[(size_t)m * 1024 + rowN];    // own-block RAW, L2-hot
                float hn = (1.f - zg) * ng + zg * hp;
                hfx[(size_t)m * 1024 + rowN] = hn;
                ushort hb = f2bf(hn);
                int ob = __shfl_xor((int)hb, 1, 64);
                if ((lane & 1) == 0)
                    *(uint*)(hdst + (size_t)m * 1024 + rowN) = (uint)hb | ((uint)ob << 16);
            }
        }
    }
    __syncthreads();   // protect red region before next tile's staging
}

// fc1 tile: 16 rows x 80 cols; A staged to LDS (sc0), 5 waves compute.
__device__ __forceinline__ void fc1_tile(
    int F, int d, uint xcc, int wave, int lane, int quad, int l16,
    const ushort* hdst, const ushort* w1p, const float* fc1_b, const float* fc2_w,
    ushort* xbfout, float* xresg, float* logitg, ushort* lds,
    float* xres, float* lacc, bool regpath)
{
    const int frow = (int)xcc * 128 + F * 16;
#pragma unroll
    for (int i = 0; i < 4; ++i) {
        const int q = wave * 4 + i, row = q >> 1, half = q & 1;
        gld16(hdst + (size_t)(frow + row) * 1024 + half * 512 + lane * 8,
              (char*)lds + row * 2064 + half * 1024);
    }
    __syncthreads();
    if (wave < 5) {
        const int jf = wave * 16 + l16;
        const ushort* fbp = w1p + (size_t)jf * 1024 + quad * 8;
        short8 bw[4];
#pragma unroll
        for (int p = 0; p < 4; ++p) bw[p] = *(const short8*)(fbp + p * 32);
        f32x4 facc = (f32x4){0.f, 0.f, 0.f, 0.f};
#pragma unroll
        for (int ks = 0; ks < 32; ++ks) {
            short8 b = bw[ks & 3];
            if (ks + 4 < 32) bw[ks & 3] = *(const short8*)(fbp + (ks + 4) * 32);
            short8 a = *(const short8*)((const char*)lds + l16 * 2064 + ks * 64 + quad * 16);
            facc = MFMA(a, b, facc, 0, 0, 0);
        }
        const float fb1 = (jf < 69) ? fc1_b[jf] : 0.f;
        const float w2v = (jf < 69) ? fc2_w[d * 69 + jf] : 0.f;
#pragma unroll
        for (int r = 0; r < 4; ++r) {
            const int m = frow + quad * 4 + r;
            float xp = regpath ? xres[r] : xresg[(size_t)m * 80 + jf];
            float o = facc[r] + xp + fb1;
            if (regpath) xres[r] = o; else xresg[(size_t)m * 80 + jf] = o;
            ushort xb = f2bf(o);
            int ob = __shfl_xor((int)xb, 1, 64);
            if ((l16 & 1) == 0)
                *(uint*)(xbfout + (size_t)m * XP + jf) = (uint)xb | ((uint)ob << 16);
            float lp = w2v * o;
            lp += __shfl_xor(lp, 8, 64);
            lp += __shfl_xor(lp, 4, 64);
            lp += __shfl_xor(lp, 2, 64);
            lp += __shfl_xor(lp, 1, 64);
            if (regpath) lacc[r] += lp;
            else if (l16 == 0) atomicAdd(logitg + m, lp);
        }
    }
    __syncthreads();
}

__global__ __launch_bounds__(512, 2) void rnn_all(
    const float* __restrict__ enc,  const float* __restrict__ dec,
    const float* __restrict__ w_ih, const float* __restrict__ w_hh,
    const float* __restrict__ b_ih, const float* __restrict__ b_hh,
    const float* __restrict__ fc1_w, const float* __restrict__ fc1_b,
    const float* __restrict__ fc2_w, const float* __restrict__ fc2_b,
    float* __restrict__ out,
    uint* bar, ushort* wpack, ushort* w1p, ushort* frames,
    ushort* hbf0, ushort* hbf1, ushort* xbfA, ushort* xbfB,
    float* hfx, float* xresg, float* logitg)
{
    __shared__ __align__(16) ushort lds[32768];   // 64 KB
    const int t = threadIdx.x, blk = blockIdx.x;
    const uint gtid = blk * 512u + t;

    uint xcc;                                      // physical XCD id (m09)
    asm volatile("s_getreg_b32 %0, hwreg(HW_REG_XCC_ID)" : "=s"(xcc));
    xcc &= 7u;
    __shared__ uint s_slot;
    if (t == 0) s_slot = __hip_atomic_fetch_add(bar + 32 + xcc * 32, 1u, AL, SC);

    // ---------------- pack phase (grid-stride) ----------------
    for (uint i = gtid; i < 884736u; i += 131072u) {        // wpack [3072][1152]
        uint row = i / 288u, c4 = (i % 288u) * 4u;
        ushort4 o; ushort* po = (ushort*)&o;
#pragma unroll
        for (int e = 0; e < 4; ++e) {
            uint k = c4 + e; float v = 0.f;
            if (k < 1024u)      v = w_hh[(size_t)row * 1024u + k];
            else if (k < 1093u) v = w_ih[(size_t)row * 69u + (k - 1024u)];
            po[e] = f2bf(v);
        }
        *(ushort4*)(wpack + (size_t)row * KP + c4) = o;
    }
    for (uint i = gtid; i < 20480u; i += 131072u) {         // w1p [80][1024]
        uint row = i / 256u, c4 = (i % 256u) * 4u;
        ushort4 o; ushort* po = (ushort*)&o;
#pragma unroll
        for (int e = 0; e < 4; ++e)
            po[e] = (row < 69u) ? f2bf(fc1_w[(size_t)row * 1024u + c4 + e]) : (ushort)0;
        *(ushort4*)(w1p + (size_t)row * 1024u + c4) = o;
    }
    for (uint i = gtid; i < 2424832u; i += 131072u) {       // frames [74][1024][128]
        uint tf = i >> 15, b = (i >> 5) & 1023u, c4 = (i & 31u) * 4u;
        ushort4 o; ushort* po = (ushort*)&o;
#pragma unroll
        for (int e = 0; e < 4; ++e) {
            uint idx = c4 + e; float v = 0.f;
            if (idx < 69u)
                v = (tf < 50u) ? enc[((size_t)b * 50u + tf) * 69u + idx]
                               : dec[((size_t)b * 24u + (tf - 50u)) * 69u + idx];
            po[e] = f2bf(v);
        }
        *(ushort4*)(frames + (size_t)tf * 131072u + (size_t)b * XP + c4) = o;
    }
    for (uint i = gtid; i < 524288u; i += 131072u) ((uint*)hbf0)[i] = 0u;
    for (uint i = gtid; i < 65536u; i += 131072u) { ((uint*)xbfA)[i] = 0u; ((uint*)xbfB)[i] = 0u; }
    for (uint i = gtid; i < 262144u; i += 131072u) ((float4*)hfx)[i] = make_float4(0.f,0.f,0.f,0.f);
    for (uint i = gtid; i < 81920u; i += 131072u) {
        uint b = i / 80u, cidx = i % 80u;
        xresg[i] = (cidx < 69u) ? enc[(size_t)b * 3450u + cidx] : 0.f;
    }
    for (uint i = gtid; i < 1024u; i += 131072u) logitg[i] = 0.f;

    globalbar(bar, bar + 16);     // ONE fenced barrier: pack visible everywhere

    const uint slot = s_slot;
    const uint c = __hip_atomic_load(bar + 32 + xcc * 32, AL, SC);  // team size (≈32)
    uint* tctr = bar + 288 + xcc * 32;
    uint* tgen = bar + 544 + xcc * 32;

    const int wave = t >> 6, lane = t & 63;
    const int wk = wave >> 2, wn = wave & 3;
    const int quad = lane >> 4, l16 = lane & 15;

    // fc1 residual/logit registers (normal path: one static tile per block)
    float xres[4], lacc[4];
    {
        const int jf = wave * 16 + l16;
#pragma unroll
        for (int r = 0; r < 4; ++r) {
            lacc[r] = 0.f;
            const int m = (int)xcc * 128 + (int)slot * 16 + quad * 4 + r;
            xres[r] = (slot < 8 && wave < 5 && jf < 69) ? enc[(size_t)m * 3450u + jf] : 0.f;
        }
    }

    // ---------------- time loop: XCD-closed recurrence ----------------
#pragma unroll 1
    for (int s = 0; s < 148; ++s) {
        const ushort* hsrc = (s & 1) ? hbf1 : hbf0;
        ushort*       hdst = (s & 1) ? hbf0 : hbf1;
        const ushort* xsrc = (s < 74) ? frames + (size_t)s * 131072u
                           : (s == 74 ? frames : (((s - 75) & 1) ? xbfB : xbfA));

#pragma unroll 1
        for (uint T = slot; T < 32u; T += c)
            gru_tile((int)T, xcc, wave, lane, wk, wn, quad, l16,
                     hsrc, xsrc, hdst, wpack, b_ih, b_hh, hfx, lds);
        teambar(tctr, tgen, c);

        if (s >= 74) {
            const int d = s - 74;
            ushort* xbfout = (d & 1) ? xbfB : xbfA;
            if (c >= 8u) {
                if (slot < 8u)
                    fc1_tile((int)slot, d, xcc, wave, lane, quad, l16, hdst, w1p,
                             fc1_b, fc2_w, xbfout, xresg, logitg, lds, xres, lacc, true);
            } else {
#pragma unroll 1
                for (uint F = slot; F < 8u; F += c)
                    fc1_tile((int)F, d, xcc, wave, lane, quad, l16, hdst, w1p,
                             fc1_b, fc2_w, xbfout, xresg, logitg, lds, xres, lacc, false);
            }
            teambar(tctr, tgen, c);
        }
    }

    // ---------------- final: sigmoid(out) per fc1 owner ----------------
    if (c >= 8u && slot < 8u) {
        float* lred = (float*)lds;
        __syncthreads();
        if (wave < 5 && l16 == 0) {
#pragma unroll
            for (int r = 0; r < 4; ++r) lred[wave * 16 + quad * 4 + r] = lacc[r];
        }
        __syncthreads();
        if (t < 16) {
            float sum = lred[t] + lred[16 + t] + lred[32 + t] + lred[48 + t] + lred[64 + t];
            const int m = (int)xcc * 128 + (int)slot * 16 + t;
            float lg = sum + fc2_b[0] + __hip_atomic_load(logitg + m, AL, SC);
            out[m] = 1.f / (1.f + __expf(-lg));
        }
    } else if (c < 8u) {
#pragma unroll 1
        for (uint F = slot; F < 8u; F += c) {
            if (t < 16) {
                const int m = (int)xcc * 128 + (int)F * 16 + t;
                float lg = fc2_b[0] + __hip_atomic_load(logitg + m, AL, SC);
                out[m] = 1.f / (1.f + __expf(-lg));
            }
        }
    }
}

extern "C" void kernel_launch(void* const* d_in, const int* in_sizes, int n_in,
                              void* d_out, int out_size, void* d_ws, size_t ws_size,
                              hipStream_t stream)
{
    const float* enc   = (const float*)d_in[0];
    const float* dec   = (const float*)d_in[1];
    const float* w_ih  = (const float*)d_in[2];
    const float* w_hh  = (const float*)d_in[3];
    const float* b_ih  = (const float*)d_in[4];
    const float* b_hh  = (const float*)d_in[5];
    const float* fc1_w = (const float*)d_in[6];
    const float* fc1_b = (const float*)d_in[7];
    const float* fc2_w = (const float*)d_in[8];
    const float* fc2_b = (const float*)d_in[9];
    float* out = (float*)d_out;

    char* ws = (char*)d_ws;
    size_t off = 0;
    auto alloc = [&](size_t bytes) -> void* {
        void* p = ws + off; off += (bytes + 255) & ~(size_t)255; return p;
    };
    uint*   bar    = (uint*)  alloc(4096);
    ushort* wpack  = (ushort*)alloc((size_t)3072 * KP * 2);
    ushort* w1p    = (ushort*)alloc((size_t)80 * 1024 * 2);
    ushort* frames = (ushort*)alloc((size_t)74 * 1024 * XP * 2);
    ushort* hbf0   = (ushort*)alloc((size_t)1024 * 1024 * 2);
    ushort* hbf1   = (ushort*)alloc((size_t)1024 * 1024 * 2);
    ushort* xbfA   = (ushort*)alloc((size_t)1024 * XP * 2);
    ushort* xbfB   = (ushort*)alloc((size_t)1024 * XP * 2);
    float*  hfx    = (float*) alloc((size_t)1024 * 1024 * 4);
    float*  xresg  = (float*) alloc((size_t)1024 * 80 * 4);
    float*  logitg = (float*) alloc((size_t)1024 * 4);

    hipMemsetAsync(bar, 0, 4096, stream);
    rnn_all<<<256, 512, 0, stream>>>(enc, dec, w_ih, w_hh, b_ih, b_hh,
                                     fc1_w, fc1_b, fc2_w, fc2_b, out,
                                     bar, wpack, w1p, frames,
                                     hbf0, hbf1, xbfA, xbfB, hfx, xresg, logitg);
}